// Round 7
// baseline (346.906 us; speedup 1.0000x reference)
//
#include <hip/hip_runtime.h>

#define S_LEN 4096
#define DIM 64
#define NHEAD 64        // B*H = 4*16
#define NCHUNK 8
#define PHEAD 4160      // 65*64 floats per head: rows e=0..63 are KV^T (e-major), row 64 = Ksum
#define LDR 68          // pass1 LDS row stride (floats)

typedef float v2f __attribute__((ext_vector_type(2)));

__device__ __forceinline__ float elu1(float x) {
    // elu(x)+1 : x>0 -> x+1 ; x<=0 -> exp(x)
    return x > 0.0f ? x + 1.0f : __expf(x);
}

// ---------------- pass 1: partial KV (64x64, e-major) + Ksum per (head, chunk) ----------
// Structure unchanged from round 6 (proven < 107 us). Inner accumulation rewritten with
// 2-wide float vectors so the backend can emit v_pk_fma_f32 (157 TF path; scalar v_fmac
// caps at 78.6 TF).
__global__ __launch_bounds__(512) void pass1_kv(
    const float* __restrict__ K, const float* __restrict__ V,
    const float* __restrict__ mask, float* __restrict__ partials)
{
    const int head = blockIdx.x >> 3;
    const int blkc = blockIdx.x & 7;
    const int t    = threadIdx.x;
    const int lane = t & 63;
    const int wave = t >> 6;          // 0..7
    const int ex   = lane & 7;        // e-group: V cols e0..e0+7
    const int dy   = lane >> 3;       // d-group: K cols d0..d0+7
    const int e0   = ex * 8;
    const int d0   = dy * 8;

    const int srow0 = blkc * 512 + wave * 64;   // this wave's first row

    __shared__ float sm[8][2][8 * LDR];         // [wave][K/V][8 rows] = 34816 B

    const long hbase = (long)head * S_LEN * DIM;

    v2f acc2[8][4];
    #pragma unroll
    for (int i = 0; i < 8; ++i)
        #pragma unroll
        for (int j = 0; j < 4; ++j) acc2[i][j] = (v2f){0.f, 0.f};
    v2f ks2[4] = {(v2f){0.f,0.f}, (v2f){0.f,0.f}, (v2f){0.f,0.f}, (v2f){0.f,0.f}};

    float4 kr[2], vr[2];
    float  mr[2];
    auto load_tile = [&](int tile) {
        const int srow = srow0 + tile * 8;
        #pragma unroll
        for (int j = 0; j < 2; ++j) {
            const int v4   = j * 64 + lane;
            const int row  = v4 >> 4;           // 0..7
            const int colg = (v4 & 15) * 4;
            kr[j] = *(const float4*)(K + hbase + (long)(srow + row) * DIM + colg);
            vr[j] = *(const float4*)(V + hbase + (long)(srow + row) * DIM + colg);
            mr[j] = mask[head * S_LEN + srow + row];
        }
    };

    float* kf = sm[wave][0];
    float* vf = sm[wave][1];

    load_tile(0);
    for (int tile = 0; tile < 8; ++tile) {
        // featurize + write current tile (regs -> LDS); same-wave ordering is program order
        #pragma unroll
        for (int j = 0; j < 2; ++j) {
            const int v4   = j * 64 + lane;
            const int row  = v4 >> 4;
            const int colg = (v4 & 15) * 4;
            float4 ko;
            ko.x = elu1(kr[j].x) * mr[j]; ko.y = elu1(kr[j].y) * mr[j];
            ko.z = elu1(kr[j].z) * mr[j]; ko.w = elu1(kr[j].w) * mr[j];
            *(float4*)&kf[row * LDR + colg] = ko;
            *(float4*)&vf[row * LDR + colg] = vr[j];
        }
        // issue next tile's global loads now; they complete under compute below
        if (tile + 1 < 8) load_tile(tile + 1);
        __builtin_amdgcn_wave_barrier();
        #pragma unroll 2
        for (int s = 0; s < 8; ++s) {
            float kk[8], vv[8];
            *(float4*)&kk[0] = *(const float4*)&kf[s * LDR + d0];
            *(float4*)&kk[4] = *(const float4*)&kf[s * LDR + d0 + 4];
            *(float4*)&vv[0] = *(const float4*)&vf[s * LDR + e0];
            *(float4*)&vv[4] = *(const float4*)&vf[s * LDR + e0 + 4];
            v2f kk2[4];
            #pragma unroll
            for (int dj = 0; dj < 4; ++dj) kk2[dj] = (v2f){kk[2*dj], kk[2*dj+1]};
            #pragma unroll
            for (int ei = 0; ei < 8; ++ei) {
                const v2f vs = (v2f){vv[ei], vv[ei]};
                #pragma unroll
                for (int dj = 0; dj < 4; ++dj)
                    acc2[ei][dj] += kk2[dj] * vs;
            }
            #pragma unroll
            for (int dj = 0; dj < 4; ++dj) ks2[dj] += kk2[dj];
        }
        __builtin_amdgcn_wave_barrier();
    }

    // -------- in-block serial reduce of the 8 wave-partials via LDS --------
    __syncthreads();
    float* red = (float*)sm;   // 4160 floats of the 34.8 KB pool
    for (int w = 0; w < 8; ++w) {
        if (wave == w) {
            if (w == 0) {
                #pragma unroll
                for (int ei = 0; ei < 8; ++ei) {
                    *(float4*)&red[(e0 + ei) * 64 + d0]     = make_float4(acc2[ei][0][0], acc2[ei][0][1], acc2[ei][1][0], acc2[ei][1][1]);
                    *(float4*)&red[(e0 + ei) * 64 + d0 + 4] = make_float4(acc2[ei][2][0], acc2[ei][2][1], acc2[ei][3][0], acc2[ei][3][1]);
                }
                if (ex == 0) {
                    *(float4*)&red[4096 + d0]     = make_float4(ks2[0][0], ks2[0][1], ks2[1][0], ks2[1][1]);
                    *(float4*)&red[4096 + d0 + 4] = make_float4(ks2[2][0], ks2[2][1], ks2[3][0], ks2[3][1]);
                }
            } else {
                #pragma unroll
                for (int ei = 0; ei < 8; ++ei) {
                    float4 a = *(float4*)&red[(e0 + ei) * 64 + d0];
                    a.x += acc2[ei][0][0]; a.y += acc2[ei][0][1]; a.z += acc2[ei][1][0]; a.w += acc2[ei][1][1];
                    *(float4*)&red[(e0 + ei) * 64 + d0] = a;
                    float4 b = *(float4*)&red[(e0 + ei) * 64 + d0 + 4];
                    b.x += acc2[ei][2][0]; b.y += acc2[ei][2][1]; b.z += acc2[ei][3][0]; b.w += acc2[ei][3][1];
                    *(float4*)&red[(e0 + ei) * 64 + d0 + 4] = b;
                }
                if (ex == 0) {
                    float4 a = *(float4*)&red[4096 + d0];
                    a.x += ks2[0][0]; a.y += ks2[0][1]; a.z += ks2[1][0]; a.w += ks2[1][1];
                    *(float4*)&red[4096 + d0] = a;
                    float4 b = *(float4*)&red[4096 + d0 + 4];
                    b.x += ks2[2][0]; b.y += ks2[2][1]; b.z += ks2[3][0]; b.w += ks2[3][1];
                    *(float4*)&red[4096 + d0 + 4] = b;
                }
            }
        }
        __syncthreads();
    }
    float* P = partials + (long)(head * NCHUNK + blkc) * PHEAD;
    for (int i = t; i < PHEAD / 4; i += 512)
        *(float4*)(P + i * 4) = *(const float4*)&red[i * 4];
}

// ---------------- reduce: sum NCHUNK partials -> final KV^T (+Ksum) per head ----------------
__global__ __launch_bounds__(256) void reduce_kv(
    const float* __restrict__ partials, float* __restrict__ kvf)
{
    const int head  = blockIdx.x >> 3;
    const int slice = blockIdx.x & 7;
    const int lo = slice * (PHEAD / 8);
    const int hi = lo + (PHEAD / 8);
    for (int idx = lo + threadIdx.x; idx < hi; idx += 256) {
        float s = 0.f;
        #pragma unroll
        for (int c = 0; c < NCHUNK; ++c)
            s += partials[((long)head * NCHUNK + c) * PHEAD + idx];
        kvf[(long)head * PHEAD + idx] = s;
    }
}

// ---------------- pass 2: out = (Qf @ KV) / (Qf . Ksum) ----------------
// Round-6 structure (proven exact traffic: FETCH 41 MB, WRITE 64 MB) + two changes:
// (1) dual-pipe KV: per cg, rows er0/er1 via s_load (SMEM pipe, proven codegen) and
//     rows er2/er3 via an 8.7 KB LDS tile staged once per block in transposed
//     [d][e-pair] layout -> one broadcast ds_read_b64 + one packed fma per d.
//     Halves the s_load dependency chain (the measured 66 us stall) and overlaps it
//     with the previously-idle LDS pipe.
// (2) packed f32: d-loops written with 2-wide float vectors -> v_pk_fma_f32.
__global__ __launch_bounds__(256) void pass2_out(
    const float* __restrict__ Q, const float* __restrict__ kvf,
    float* __restrict__ out)
{
    const int head = blockIdx.x >> 6;     // 64 tiles of 64 rows per head
    const int tile = blockIdx.x & 63;
    const int t    = threadIdx.x;
    const int lane = t & 63;
    const int wave = t >> 6;

    __shared__ float o_sl[64 * 64];       // swizzled output tile, 16 KB
    __shared__ float kv_sl[64 * 34];      // KV rows e%4 in {2,3}, transposed [d][pair], 8.7 KB

    const long hbase = (long)head * S_LEN * DIM;
    const int  rbase = tile * 64;
    const int  row   = rbase + lane;      // this lane's row (same set for all 4 waves)

    const float* __restrict__ kvt = kvf + (long)head * PHEAD;

    // (a0) stage er2/er3 rows of every cg into LDS, transposed: kv_sl[d*34 + idx]
    //      where idx = 2*cg + (e&1), e = 4*cg + 2 + (e&1). Coalesced global reads
    //      (row-major), 4-way-bank LDS writes on 8 insts (negligible, once per block).
    #pragma unroll
    for (int i = 0; i < 8; ++i) {
        const int ii  = i * 256 + t;      // 0..2047
        const int idx = ii >> 6;          // 0..31
        const int d   = ii & 63;
        const int e   = (idx >> 1) * 4 + 2 + (idx & 1);
        kv_sl[d * 34 + idx] = kvt[e * 64 + d];
    }

    // (a) pull own Qf row into registers (packed pairs), elu+1 on the fly
    const float* __restrict__ qrow = Q + hbase + (long)row * DIM;
    v2f q2[32];
    #pragma unroll
    for (int i = 0; i < 16; ++i) {
        const float4 v = *(const float4*)(qrow + i * 4);
        q2[i * 2 + 0] = (v2f){elu1(v.x), elu1(v.y)};
        q2[i * 2 + 1] = (v2f){elu1(v.z), elu1(v.w)};
    }
    __syncthreads();   // kv_sl ready

    // (b) denominator: Qf . Ksum — uniform address -> scalar loads
    const float* __restrict__ ksum = kvt + 64 * 64;
    v2f dn = (v2f){0.f, 0.f};
    #pragma unroll
    for (int dj = 0; dj < 32; ++dj)
        dn += q2[dj] * *(const v2f*)&ksum[dj * 2];
    const float rz = 1.0f / (dn[0] + dn[1]);

    // (c) this wave's 4 column-groups; cg0 pinned to SGPR -> er0/er1 stay s_load
    const int cg0 = __builtin_amdgcn_readfirstlane(wave) * 4;
    #pragma unroll 1
    for (int j = 0; j < 4; ++j) {
        const int cg = cg0 + j;                         // block-uniform per wave
        const float* __restrict__ r = kvt + cg * 256;   // rows e = 4*cg .. 4*cg+3
        // er0/er1: scalar-pipe path
        v2f s0 = (v2f){0.f, 0.f}, s1 = (v2f){0.f, 0.f};
        #pragma unroll
        for (int dj = 0; dj < 32; ++dj) {
            s0 += q2[dj] * *(const v2f*)&r[dj * 2];
            s1 += q2[dj] * *(const v2f*)&r[64 + dj * 2];
        }
        // er2/er3: LDS-broadcast path, packed pair per d
        v2f s23 = (v2f){0.f, 0.f};
        #pragma unroll
        for (int d = 0; d < 64; ++d) {
            const v2f kv2 = *(const v2f*)&kv_sl[d * 34 + 2 * cg];
            const float qd = q2[d >> 1][d & 1];
            s23 += kv2 * (v2f){qd, qd};
        }
        *(float4*)&o_sl[lane * 64 + ((cg ^ (lane & 15)) * 4)] =
            make_float4((s0[0] + s0[1]) * rz, (s1[0] + s1[1]) * rz,
                        s23[0] * rz, s23[1] * rz);
    }
    __syncthreads();

    // (d) readback (unswizzle) + full 256 B row coalesced stores (exact HBM traffic)
    #pragma unroll
    for (int i = 0; i < 4; ++i) {
        const int v4   = i * 256 + t;
        const int orow = v4 >> 4;
        const int g    = v4 & 15;
        const float4 o = *(const float4*)&o_sl[orow * 64 + ((g ^ (orow & 15)) * 4)];
        *(float4*)(out + hbase + (long)(rbase + orow) * DIM + g * 4) = o;
    }
}

extern "C" void kernel_launch(void* const* d_in, const int* in_sizes, int n_in,
                              void* d_out, int out_size, void* d_ws, size_t ws_size,
                              hipStream_t stream) {
    const float* Q    = (const float*)d_in[0];
    const float* K    = (const float*)d_in[1];
    const float* V    = (const float*)d_in[2];
    const float* mask = (const float*)d_in[3];
    float* out = (float*)d_out;

    float* partials = (float*)d_ws;                            // 64*8*4160 floats ≈ 8.5 MB
    float* kvf = partials + (size_t)NHEAD * NCHUNK * PHEAD;    // + ≈1.1 MB (proven fit)

    pass1_kv<<<NHEAD * NCHUNK, 512, 0, stream>>>(K, V, mask, partials);
    reduce_kv<<<NHEAD * 8, 256, 0, stream>>>(partials, kvf);
    pass2_out<<<NHEAD * 64, 256, 0, stream>>>(Q, kvf, out);
}